// Round 8
// baseline (270.006 us; speedup 1.0000x reference)
//
#include <hip/hip_runtime.h>
#include <hip/hip_bf16.h>
#include <stdint.h>

// Problem constants: N=8, CIN=512, COUT=512, K=3, H=W=64
// out = demod[n,co]*sqrt2 * conv(cw, s[n,ci]*x) + nw*noise + bias, leaky(0.2)

typedef __attribute__((ext_vector_type(8))) short short8;
typedef __attribute__((ext_vector_type(4))) float f32x4;
typedef __attribute__((ext_vector_type(16))) float f32x16;
typedef __attribute__((ext_vector_type(4))) unsigned int uint4v;
typedef __attribute__((ext_vector_type(2))) unsigned int uint2v;

__device__ __forceinline__ unsigned short f2bf(float f) {
  unsigned u = __builtin_bit_cast(unsigned, f);
  u += 0x7FFFu + ((u >> 16) & 1u);   // round-to-nearest-even
  return (unsigned short)(u >> 16);
}

__device__ __forceinline__ void g2l16(const void* g, void* l) {
  __builtin_amdgcn_global_load_lds(
      (const __attribute__((address_space(1))) void*)g,
      (__attribute__((address_space(3))) void*)l, 16, 0, 0);
}

// ---------------- k_pre: style GEMV (0..1023) | wsq (1024..2047) ----------------
// EXACT R0 code (verified).
__global__ void k_pre(const float* __restrict__ style, const float* __restrict__ mw,
                      const float* __restrict__ mb, const float* __restrict__ cw,
                      float* __restrict__ s_out, float* __restrict__ wsq) {
  int t = threadIdx.x;
  int b = blockIdx.x;
  if (b < 1024) {
    int wid = b * 4 + (t >> 6);   // (n,ci), 4096 total
    int lane = t & 63;
    int n = wid >> 9, ci = wid & 511;
    float sum = 0.f;
#pragma unroll
    for (int i = 0; i < 8; ++i) {
      int k = lane + i * 64;
      sum += style[n * 512 + k] * mw[ci * 512 + k];
    }
#pragma unroll
    for (int off = 32; off; off >>= 1) sum += __shfl_xor(sum, off, 64);
    if (lane == 0) s_out[wid] = sum + mb[ci];
  } else {
    int id = (b - 1024) * 256 + t;   // (co,ci), 262144 total
    const float* p = cw + (size_t)id * 9;
    float a = 0.f;
#pragma unroll
    for (int j = 0; j < 9; ++j) a += p[j] * p[j];
    wsq[id] = a;
  }
}

// ---------------- k_mid: xpad(0..511) | demod(512..1535) | Wt(1536..1791) | halo --
// xpad/demod/halo byte-identical (verified). Wt layout FOR 32x32x16 MFMA:
// [cb 16][kb 16]{ [tap 9][lhi 4][co 32][8ci] } bf16, tile 18432 B.
//   (lhi = ks*2 + hi; A-frag lane: co=lane&31, ci = lhi*8+j)
// Xp layout: [n 8][row 66][kb 16][lhi 4][col 66][8] bf16 (unchanged).
__global__ void k_mid(const float* __restrict__ s, const float* __restrict__ wsq,
                      const float* __restrict__ x, const float* __restrict__ cw,
                      float* __restrict__ demod, unsigned short* __restrict__ Xp,
                      unsigned short* __restrict__ Wt) {
  __shared__ char smem[74240];
  int t = threadIdx.x;
  int b = blockIdx.x;
  if (b < 512) {
    // ---- xpad: block (n,h): all 512 ci, 64 cols. float4 loads, bf16 LDS tile ----
    int n = b >> 6, h = b & 63;
    short* ldsx = (short*)smem;              // [ci 512][68]  69632 B
    float* sxf = (float*)(smem + 69632);     // [512]
    sxf[t] = s[n * 512 + t];
    sxf[t + 256] = s[n * 512 + 256 + t];
    __syncthreads();
    const float* xb = x + ((size_t)n * 512) * 4096 + h * 64;
#pragma unroll
    for (int i = 0; i < 32; ++i) {
      int L = t + i * 256;
      int ci = L >> 4, q = L & 15;
      f32x4 v = *(const f32x4*)(xb + (size_t)ci * 4096 + q * 4);
      float sv = sxf[ci];
      uint2v o;
      o.x = f2bf(v.x * sv) | ((unsigned)f2bf(v.y * sv) << 16);
      o.y = f2bf(v.z * sv) | ((unsigned)f2bf(v.w * sv) << 16);
      *(uint2v*)(ldsx + ci * 68 + q * 4) = o;
    }
    __syncthreads();
    unsigned short* nb = Xp + (size_t)n * 2230272 + (size_t)(h + 1) * 33792;
#pragma unroll
    for (int r = 0; r < 16; ++r) {
      int u = t + r * 256;
      int cig = u >> 6, col = u & 63;   // cig = kb*4+lhi (ci = cig*8+j)
      unsigned v[8];
#pragma unroll
      for (int j = 0; j < 8; ++j)
        v[j] = (unsigned short)ldsx[(cig * 8 + j) * 68 + col];
      uint4v o;
      o.x = v[0] | (v[1] << 16);
      o.y = v[2] | (v[3] << 16);
      o.z = v[4] | (v[5] << 16);
      o.w = v[6] | (v[7] << 16);
      *(uint4v*)(nb + ((size_t)cig * 66 + col + 1) * 8) = o;
    }
  } else if (b < 1536) {
    // ---- demod ----
    int wid = (b - 512) * 4 + (t >> 6);   // (n,co)
    int lane = t & 63;
    int n = wid >> 9, co = wid & 511;
    float sum = 0.f;
#pragma unroll
    for (int i = 0; i < 8; ++i) {
      int ci = lane + i * 64;
      float sv = s[n * 512 + ci];
      sum += sv * sv * wsq[co * 512 + ci];
    }
#pragma unroll
    for (int off = 32; off; off >>= 1) sum += __shfl_xor(sum, off, 64);
    if (lane == 0) demod[wid] = rsqrtf(sum + 1e-8f) * 1.41421356237309515f;
  } else if (b < 1792) {
    // ---- Wt build: one block per (cb32,kb); LDS [32][289] floats, conflict-free --
    int bb = b - 1536;
    int cb = bb >> 4, kb = bb & 15;      // cb 0..15 (32-co tiles)
    float* ldsf = (float*)smem;          // [32][289]  36992 B
#pragma unroll
    for (int i = 0; i < 36; ++i) {
      int idx = t + i * 256;             // 0..9215
      int seg = idx / 288, off = idx - seg * 288;
      ldsf[seg * 289 + off] = cw[(size_t)(cb * 32 + seg) * 4608 + kb * 288 + off];
    }
    __syncthreads();
    unsigned short* ob = Wt + (size_t)(cb * 16 + kb) * 9216;
#pragma unroll
    for (int i = 0; i < 5; ++i) {
      int c = t + i * 256;               // chunk 0..1151 = (tap*4+lhi)*32+co_rel
      if (c < 1152) {
        int co_rel = c & 31, lhi = (c >> 5) & 3, tap = c >> 7;
        unsigned v[8];
#pragma unroll
        for (int j = 0; j < 8; ++j)
          v[j] = f2bf(ldsf[co_rel * 289 + (lhi * 8 + j) * 9 + tap]);
        uint4v o;
        o.x = v[0] | (v[1] << 16);
        o.y = v[2] | (v[3] << 16);
        o.z = v[4] | (v[5] << 16);
        o.w = v[6] | (v[7] << 16);
        *(uint4v*)(ob + (size_t)c * 8) = o;
      }
    }
  } else {
    // ---- halo zero: 16640 16B-chunks per n; 17 parts x 1024 chunks ----
    int bb = b - 1792;
    int n = bb / 17, part = bb % 17;
    uint4v z = (uint4v){0u, 0u, 0u, 0u};
    unsigned short* base = Xp + (size_t)n * 2230272;
#pragma unroll
    for (int i = 0; i < 4; ++i) {
      int id = part * 1024 + i * 256 + t;
      if (id < 16640) {
        size_t off;
        if (id < 8448) {                 // rows 0 and 65, full rows
          int row = (id < 4224) ? 0 : 65;
          int c = id - ((id < 4224) ? 0 : 4224);
          off = (size_t)row * 33792 + (size_t)c * 8;
        } else {                         // cols 0 and 65, rows 1..64
          int id2 = id - 8448;
          int row = 1 + (id2 >> 7);
          int rem = id2 & 127;
          int klhi = rem >> 1;
          int col = (rem & 1) ? 65 : 0;
          off = (size_t)row * 33792 + ((size_t)klhi * 66 + col) * 8;
        }
        *(uint4v*)(base + off) = z;
      }
    }
  }
}

// ---------------- k_conv: 32x32x16 MFMA, 32co x 6row x 64col, 3 blocks/CU -------
// Matrix-pipe floor drops 74.5 -> 62 us (m119: 2495 vs 2176 TF); LDS bytes/FLOP
// halves. XCD-pinned swizzle: n = wgid&7 (one n's Xp per XCD L2), rx-fastest.
// Wave wv: col-half ch=wv>>1 (32 cols), row-group rg=wv&1 (3 rows).
// A-frag: lane holds W[co=lane&31][ci=(ks*2+hi)*8+j], hi=lane>>5.
// B-frag: lane holds X[ci][col=ch*32+(lane&31)+dw] (8 ci contiguous).
// C/D: col=lane&31, co_rel=(reg&3)+8*(reg>>2)+4*hi  [HW-verified m74/m101].
__global__ void __launch_bounds__(256, 3) k_conv(
    const unsigned short* __restrict__ Wt, const unsigned short* __restrict__ Xp,
    const float* __restrict__ demod, const float* __restrict__ noise,
    const float* __restrict__ nw_p, const float* __restrict__ act_bias,
    float* __restrict__ out) {
  __shared__ short lds_a[9216];    // 18432 B  [tap 9][lhi 4][co 32][8ci]
  __shared__ short lds_x[16896];   // 33792 B  [row 8][lhi 4][pcol 66][8ci]
  int t = threadIdx.x;
  int wg = blockIdx.x;             // 1408 = 8n x 16cb x 11rx
  int n = wg & 7;                  // XCD-pinned (round-robin dispatch)
  int rem = wg >> 3;               // rx-fastest within XCD
  int cb = rem / 11;
  int bx = rem - cb * 11;
  int r0 = (bx < 10) ? bx * 6 : 58;   // tail overlaps rows 58-59 (benign)
  int lane = t & 63, wv = t >> 6;
  int l31 = lane & 31, hi = lane >> 5;
  int ch = wv >> 1, rg = wv & 1;

  const unsigned short* abase = Wt + (size_t)cb * 16 * 9216;
  const unsigned short* xbase = Xp + (size_t)n * 2230272;
  int xoffg[9];
#pragma unroll
  for (int j = 0; j < 9; ++j) {
    int c = j * 256 + t;           // 8 rows x 264 chunks = 2112
    int r = c / 264, rc = c - r * 264;
    int off = (r0 + r) * 33792 + rc * 8;
    if (c >= 2112) off = 0;
    xoffg[j] = off;
  }

  f32x16 acc[3];
#pragma unroll
  for (int r = 0; r < 3; ++r)
#pragma unroll
    for (int q = 0; q < 16; ++q) acc[r][q] = 0.f;

  const int aoff = hi * 256 + l31 * 8;              // + tap*1024 + ks*512
  const int xb0 = hi * 528 + ch * 256 + l31 * 8;    // + row*2112 + ks*1056 + dw*8

  for (int kb = 0; kb < 16; ++kb) {
    __syncthreads();
    const char* ab = (const char*)(abase + (size_t)kb * 9216);
#pragma unroll
    for (int i = 0; i < 5; ++i) {
      int c = i * 256 + t;         // 1152 chunks of 16B
      if (c < 1152) g2l16(ab + c * 16, (char*)lds_a + c * 16);
    }
#pragma unroll
    for (int j = 0; j < 9; ++j) {
      int c = j * 256 + t;         // 2112 chunks of 16B
      if (c < 2112) g2l16(xbase + xoffg[j] + kb * 2112, (char*)lds_x + c * 16);
    }
    __syncthreads();

#pragma unroll
    for (int dw = 0; dw < 3; ++dw) {
      short8 bf[5][2];
#pragma unroll
      for (int rr = 0; rr < 5; ++rr)
#pragma unroll
        for (int ks = 0; ks < 2; ++ks)
          bf[rr][ks] = *(const short8*)(lds_x + (rg * 3 + rr) * 2112 + ks * 1056 +
                                        dw * 8 + xb0);
#pragma unroll
      for (int dh = 0; dh < 3; ++dh) {
        int tap = dh * 3 + dw;
#pragma unroll
        for (int ks = 0; ks < 2; ++ks) {
          short8 af = *(const short8*)(lds_a + tap * 1024 + ks * 512 + aoff);
#pragma unroll
          for (int r = 0; r < 3; ++r)
            acc[r] = __builtin_amdgcn_mfma_f32_32x32x16_bf16(af, bf[r + dh][ks],
                                                             acc[r], 0, 0, 0);
        }
      }
    }
  }

  float nw = nw_p[0];
  int col = ch * 32 + l31;
  f32x4 dm4[4], ab4[4];
#pragma unroll
  for (int q = 0; q < 4; ++q) {
    dm4[q] = *(const f32x4*)(demod + n * 512 + cb * 32 + q * 8 + hi * 4);
    ab4[q] = *(const f32x4*)(act_bias + cb * 32 + q * 8 + hi * 4);
  }
#pragma unroll
  for (int r = 0; r < 3; ++r) {
    int R = r0 + rg * 3 + r;
    float nz = nw * noise[((size_t)n * 64 + R) * 64 + col];
#pragma unroll
    for (int q = 0; q < 4; ++q) {
#pragma unroll
      for (int c = 0; c < 4; ++c) {
        int co = cb * 32 + q * 8 + hi * 4 + c;
        float v = dm4[q][c] * acc[r][q * 4 + c] + nz + ab4[q][c];
        v = v > 0.f ? v : 0.2f * v;
        out[(((size_t)n * 512 + co) * 64 + R) * 64 + col] = v;
      }
    }
  }
}

extern "C" void kernel_launch(void* const* d_in, const int* in_sizes, int n_in,
                              void* d_out, int out_size, void* d_ws, size_t ws_size,
                              hipStream_t stream) {
  const float* x     = (const float*)d_in[0];
  const float* style = (const float*)d_in[1];
  const float* noise = (const float*)d_in[2];
  const float* cw    = (const float*)d_in[3];
  const float* mw    = (const float*)d_in[4];
  const float* mb    = (const float*)d_in[5];
  const float* nw    = (const float*)d_in[6];
  const float* ab    = (const float*)d_in[7];
  float* out = (float*)d_out;

  char* ws = (char*)d_ws;
  float* s_buf  = (float*)ws;                            // 16 KB
  float* demod  = (float*)(ws + 16384);                  // 16 KB
  float* wsq    = (float*)(ws + 32768);                  // 1 MB
  unsigned short* Wt = (unsigned short*)(ws + 1081344);  // 4,718,592 B
  unsigned short* Xp = (unsigned short*)(ws + 5799936);  // 35,684,352 B (end 41.5 MB)

  k_pre<<<2048, 256, 0, stream>>>(style, mw, mb, cw, s_buf, wsq);
  k_mid<<<1928, 256, 0, stream>>>(s_buf, wsq, x, cw, demod, Xp, Wt);
  k_conv<<<1408, 256, 0, stream>>>(Wt, Xp, demod, noise, nw, ab, out);
}

// Round 9
// 258.231 us; speedup vs baseline: 1.0456x; 1.0456x over previous
//
#include <hip/hip_runtime.h>
#include <hip/hip_bf16.h>
#include <stdint.h>

// Problem constants: N=8, CIN=512, COUT=512, K=3, H=W=64
// out = demod[n,co]*sqrt2 * conv(cw, s[n,ci]*x) + nw*noise + bias, leaky(0.2)

typedef __attribute__((ext_vector_type(8))) short short8;
typedef __attribute__((ext_vector_type(4))) float f32x4;
typedef __attribute__((ext_vector_type(16))) float f32x16;
typedef __attribute__((ext_vector_type(4))) unsigned int uint4v;
typedef __attribute__((ext_vector_type(2))) unsigned int uint2v;

__device__ __forceinline__ unsigned short f2bf(float f) {
  unsigned u = __builtin_bit_cast(unsigned, f);
  u += 0x7FFFu + ((u >> 16) & 1u);   // round-to-nearest-even
  return (unsigned short)(u >> 16);
}

__device__ __forceinline__ void g2l16(const void* g, void* l) {
  __builtin_amdgcn_global_load_lds(
      (const __attribute__((address_space(1))) void*)g,
      (__attribute__((address_space(3))) void*)l, 16, 0, 0);
}

// ---------------- k_pre: style GEMV (0..1023) | wsq (1024..2047) ----------------
// EXACT R0 code (verified).
__global__ void k_pre(const float* __restrict__ style, const float* __restrict__ mw,
                      const float* __restrict__ mb, const float* __restrict__ cw,
                      float* __restrict__ s_out, float* __restrict__ wsq) {
  int t = threadIdx.x;
  int b = blockIdx.x;
  if (b < 1024) {
    int wid = b * 4 + (t >> 6);   // (n,ci), 4096 total
    int lane = t & 63;
    int n = wid >> 9, ci = wid & 511;
    float sum = 0.f;
#pragma unroll
    for (int i = 0; i < 8; ++i) {
      int k = lane + i * 64;
      sum += style[n * 512 + k] * mw[ci * 512 + k];
    }
#pragma unroll
    for (int off = 32; off; off >>= 1) sum += __shfl_xor(sum, off, 64);
    if (lane == 0) s_out[wid] = sum + mb[ci];
  } else {
    int id = (b - 1024) * 256 + t;   // (co,ci), 262144 total
    const float* p = cw + (size_t)id * 9;
    float a = 0.f;
#pragma unroll
    for (int j = 0; j < 9; ++j) a += p[j] * p[j];
    wsq[id] = a;
  }
}

// ---------------- k_mid: xpad(0..511) | demod(512..1535) | Wt(1536..1791) | halo --
// EXACT R8 code (verified, incl. 32x32-MFMA Wt layout):
// Wt: [cb32 16][kb 16]{ [tap 9][lhi 4][co 32][8ci] } bf16, tile 18432 B.
// Xp: [n 8][row 66][kb 16][lhi 4][col 66][8] bf16.
__global__ void k_mid(const float* __restrict__ s, const float* __restrict__ wsq,
                      const float* __restrict__ x, const float* __restrict__ cw,
                      float* __restrict__ demod, unsigned short* __restrict__ Xp,
                      unsigned short* __restrict__ Wt) {
  __shared__ char smem[74240];
  int t = threadIdx.x;
  int b = blockIdx.x;
  if (b < 512) {
    // ---- xpad: block (n,h): all 512 ci, 64 cols. float4 loads, bf16 LDS tile ----
    int n = b >> 6, h = b & 63;
    short* ldsx = (short*)smem;              // [ci 512][68]  69632 B
    float* sxf = (float*)(smem + 69632);     // [512]
    sxf[t] = s[n * 512 + t];
    sxf[t + 256] = s[n * 512 + 256 + t];
    __syncthreads();
    const float* xb = x + ((size_t)n * 512) * 4096 + h * 64;
#pragma unroll
    for (int i = 0; i < 32; ++i) {
      int L = t + i * 256;
      int ci = L >> 4, q = L & 15;
      f32x4 v = *(const f32x4*)(xb + (size_t)ci * 4096 + q * 4);
      float sv = sxf[ci];
      uint2v o;
      o.x = f2bf(v.x * sv) | ((unsigned)f2bf(v.y * sv) << 16);
      o.y = f2bf(v.z * sv) | ((unsigned)f2bf(v.w * sv) << 16);
      *(uint2v*)(ldsx + ci * 68 + q * 4) = o;
    }
    __syncthreads();
    unsigned short* nb = Xp + (size_t)n * 2230272 + (size_t)(h + 1) * 33792;
#pragma unroll
    for (int r = 0; r < 16; ++r) {
      int u = t + r * 256;
      int cig = u >> 6, col = u & 63;   // cig = kb*4+lhi (ci = cig*8+j)
      unsigned v[8];
#pragma unroll
      for (int j = 0; j < 8; ++j)
        v[j] = (unsigned short)ldsx[(cig * 8 + j) * 68 + col];
      uint4v o;
      o.x = v[0] | (v[1] << 16);
      o.y = v[2] | (v[3] << 16);
      o.z = v[4] | (v[5] << 16);
      o.w = v[6] | (v[7] << 16);
      *(uint4v*)(nb + ((size_t)cig * 66 + col + 1) * 8) = o;
    }
  } else if (b < 1536) {
    // ---- demod ----
    int wid = (b - 512) * 4 + (t >> 6);   // (n,co)
    int lane = t & 63;
    int n = wid >> 9, co = wid & 511;
    float sum = 0.f;
#pragma unroll
    for (int i = 0; i < 8; ++i) {
      int ci = lane + i * 64;
      float sv = s[n * 512 + ci];
      sum += sv * sv * wsq[co * 512 + ci];
    }
#pragma unroll
    for (int off = 32; off; off >>= 1) sum += __shfl_xor(sum, off, 64);
    if (lane == 0) demod[wid] = rsqrtf(sum + 1e-8f) * 1.41421356237309515f;
  } else if (b < 1792) {
    // ---- Wt build: one block per (cb32,kb); LDS [32][289] floats, conflict-free --
    int bb = b - 1536;
    int cb = bb >> 4, kb = bb & 15;      // cb 0..15 (32-co tiles)
    float* ldsf = (float*)smem;          // [32][289]  36992 B
#pragma unroll
    for (int i = 0; i < 36; ++i) {
      int idx = t + i * 256;             // 0..9215
      int seg = idx / 288, off = idx - seg * 288;
      ldsf[seg * 289 + off] = cw[(size_t)(cb * 32 + seg) * 4608 + kb * 288 + off];
    }
    __syncthreads();
    unsigned short* ob = Wt + (size_t)(cb * 16 + kb) * 9216;
#pragma unroll
    for (int i = 0; i < 5; ++i) {
      int c = t + i * 256;               // chunk 0..1151 = (tap*4+lhi)*32+co_rel
      if (c < 1152) {
        int co_rel = c & 31, lhi = (c >> 5) & 3, tap = c >> 7;
        unsigned v[8];
#pragma unroll
        for (int j = 0; j < 8; ++j)
          v[j] = f2bf(ldsf[co_rel * 289 + (lhi * 8 + j) * 9 + tap]);
        uint4v o;
        o.x = v[0] | (v[1] << 16);
        o.y = v[2] | (v[3] << 16);
        o.z = v[4] | (v[5] << 16);
        o.w = v[6] | (v[7] << 16);
        *(uint4v*)(ob + (size_t)c * 8) = o;
      }
    }
  } else {
    // ---- halo zero: 16640 16B-chunks per n; 17 parts x 1024 chunks ----
    int bb = b - 1792;
    int n = bb / 17, part = bb % 17;
    uint4v z = (uint4v){0u, 0u, 0u, 0u};
    unsigned short* base = Xp + (size_t)n * 2230272;
#pragma unroll
    for (int i = 0; i < 4; ++i) {
      int id = part * 1024 + i * 256 + t;
      if (id < 16640) {
        size_t off;
        if (id < 8448) {                 // rows 0 and 65, full rows
          int row = (id < 4224) ? 0 : 65;
          int c = id - ((id < 4224) ? 0 : 4224);
          off = (size_t)row * 33792 + (size_t)c * 8;
        } else {                         // cols 0 and 65, rows 1..64
          int id2 = id - 8448;
          int row = 1 + (id2 >> 7);
          int rem = id2 & 127;
          int klhi = rem >> 1;
          int col = (rem & 1) ? 65 : 0;
          off = (size_t)row * 33792 + ((size_t)klhi * 66 + col) * 8;
        }
        *(uint4v*)(base + off) = z;
      }
    }
  }
}

// ---------------- k_conv: 32x32x16, 64co x 8row x 64col, 80 KB, 2 blocks/CU ------
// Per wave: M=2 co-tiles x 4 rows x 32 cols -> 144 MFMA / 72 ds_read_b128 per kb
// (0.50 reads/MFMA, -44% vs R8). MFMA demand now EXCEEDS LDS demand per CU-kb.
// Grid 512 = exactly 2 blocks/CU, zero tail. n = wg&7 -> XCD-pinned (R8-verified).
// 8 independent acc chains (reuse distance 64 cy) -> no MFMA dep stalls.
// All fragment mappings byte-identical to R8 (HW-verified).
__global__ void __launch_bounds__(256, 2) k_conv(
    const unsigned short* __restrict__ Wt, const unsigned short* __restrict__ Xp,
    const float* __restrict__ demod, const float* __restrict__ noise,
    const float* __restrict__ nw_p, const float* __restrict__ act_bias,
    float* __restrict__ out) {
  __shared__ short lds_a[18432];   // 36864 B  [m 2][tap 9][lhi 4][co 32][8ci]
  __shared__ short lds_x[22528];   // 45056 B  [row 10][lhi 4][pcol 66][8ci] (+pad)
  int t = threadIdx.x;
  int wg = blockIdx.x;             // 512 = 8n x 8rx x 8cb
  int n = wg & 7;                  // XCD-pinned (round-robin dispatch)
  int rem = wg >> 3;
  int rx = rem & 7;                // rx fastest within XCD
  int cb = rem >> 3;               // cb 0..7 (64-co tiles)
  int r0 = rx * 8;
  int lane = t & 63, wv = t >> 6;
  int l31 = lane & 31, hi = lane >> 5;
  int ch = wv & 1, rg = wv >> 1;   // col-half, row-group (4 rows each)

  const char* ab0 = (const char*)(Wt + (size_t)((cb * 2) * 16) * 9216);
  const char* ab1 = (const char*)(Wt + (size_t)((cb * 2 + 1) * 16) * 9216);
  const unsigned short* xbase = Xp + (size_t)n * 2230272;
  int xoffg[11];
#pragma unroll
  for (int j = 0; j < 11; ++j) {
    int c = j * 256 + t;           // 10 rows x 264 chunks = 2640
    int r = c / 264, rc = c - r * 264;
    int off = (r0 + r) * 33792 + rc * 8;
    if (c >= 2640) off = 0;        // tail lanes read row 0 into pad slots
    xoffg[j] = off;
  }

  f32x16 acc[2][4];
#pragma unroll
  for (int m = 0; m < 2; ++m)
#pragma unroll
    for (int r = 0; r < 4; ++r)
#pragma unroll
      for (int q = 0; q < 16; ++q) acc[m][r][q] = 0.f;

  const int aoff = hi * 256 + l31 * 8;              // + m*9216 + tap*1024 + ks*512
  const int xb0 = hi * 528 + ch * 256 + l31 * 8;    // + row*2112 + ks*1056 + dw*8

  for (int kb = 0; kb < 16; ++kb) {
    __syncthreads();
#pragma unroll
    for (int i = 0; i < 9; ++i) {
      int c = i * 256 + t;         // 2304 chunks: m0 = 0..1151, m1 = 1152..2303
      const char* src = (c < 1152) ? (ab0 + (size_t)kb * 18432 + c * 16)
                                   : (ab1 + (size_t)kb * 18432 + (c - 1152) * 16);
      g2l16(src, (char*)lds_a + c * 16);
    }
#pragma unroll
    for (int j = 0; j < 11; ++j)
      g2l16(xbase + xoffg[j] + kb * 2112, (char*)lds_x + j * 4096 + t * 16);
    __syncthreads();

#pragma unroll
    for (int dw = 0; dw < 3; ++dw) {
      short8 bf[6][2];
#pragma unroll
      for (int rr = 0; rr < 6; ++rr)
#pragma unroll
        for (int ks = 0; ks < 2; ++ks)
          bf[rr][ks] = *(const short8*)(lds_x + (rg * 4 + rr) * 2112 + ks * 1056 +
                                        dw * 8 + xb0);
#pragma unroll
      for (int dh = 0; dh < 3; ++dh) {
        int tap = dh * 3 + dw;
#pragma unroll
        for (int ks = 0; ks < 2; ++ks) {
#pragma unroll
          for (int m = 0; m < 2; ++m) {
            short8 af = *(const short8*)(lds_a + m * 9216 + tap * 1024 + ks * 512 + aoff);
#pragma unroll
            for (int r = 0; r < 4; ++r)
              acc[m][r] = __builtin_amdgcn_mfma_f32_32x32x16_bf16(af, bf[r + dh][ks],
                                                                  acc[m][r], 0, 0, 0);
          }
        }
      }
    }
  }

  float nw = nw_p[0];
  int col = ch * 32 + l31;
  f32x4 dm4[2][4], ab4[2][4];
#pragma unroll
  for (int m = 0; m < 2; ++m)
#pragma unroll
    for (int q = 0; q < 4; ++q) {
      dm4[m][q] = *(const f32x4*)(demod + n * 512 + cb * 64 + m * 32 + q * 8 + hi * 4);
      ab4[m][q] = *(const f32x4*)(act_bias + cb * 64 + m * 32 + q * 8 + hi * 4);
    }
#pragma unroll
  for (int r = 0; r < 4; ++r) {
    int R = r0 + rg * 4 + r;
    float nz = nw * noise[((size_t)n * 64 + R) * 64 + col];
#pragma unroll
    for (int m = 0; m < 2; ++m) {
#pragma unroll
      for (int q = 0; q < 4; ++q) {
#pragma unroll
        for (int c = 0; c < 4; ++c) {
          int co = cb * 64 + m * 32 + q * 8 + hi * 4 + c;
          float v = dm4[m][q][c] * acc[m][r][q * 4 + c] + nz + ab4[m][q][c];
          v = v > 0.f ? v : 0.2f * v;
          out[(((size_t)n * 512 + co) * 64 + R) * 64 + col] = v;
        }
      }
    }
  }
}

extern "C" void kernel_launch(void* const* d_in, const int* in_sizes, int n_in,
                              void* d_out, int out_size, void* d_ws, size_t ws_size,
                              hipStream_t stream) {
  const float* x     = (const float*)d_in[0];
  const float* style = (const float*)d_in[1];
  const float* noise = (const float*)d_in[2];
  const float* cw    = (const float*)d_in[3];
  const float* mw    = (const float*)d_in[4];
  const float* mb    = (const float*)d_in[5];
  const float* nw    = (const float*)d_in[6];
  const float* ab    = (const float*)d_in[7];
  float* out = (float*)d_out;

  char* ws = (char*)d_ws;
  float* s_buf  = (float*)ws;                            // 16 KB
  float* demod  = (float*)(ws + 16384);                  // 16 KB
  float* wsq    = (float*)(ws + 32768);                  // 1 MB
  unsigned short* Wt = (unsigned short*)(ws + 1081344);  // 4,718,592 B
  unsigned short* Xp = (unsigned short*)(ws + 5799936);  // 35,684,352 B (end 41.5 MB)

  k_pre<<<2048, 256, 0, stream>>>(style, mw, mb, cw, s_buf, wsq);
  k_mid<<<1928, 256, 0, stream>>>(s_buf, wsq, x, cw, demod, Xp, Wt);
  k_conv<<<512, 256, 0, stream>>>(Wt, Xp, demod, noise, nw, ab, out);
}